// Round 3
// baseline (445.489 us; speedup 1.0000x reference)
//
#include <hip/hip_runtime.h>

#define N 8192
#define F_IN 256
#define F_OUT 64
#define ALPHA 0.2f
#define LOG2E 1.4426950408889634f
#define COFF 80.0f   // weight-scale offset: w = exp2(e - Brow + COFF) <= 2^80

typedef __attribute__((ext_vector_type(8))) short bf16x8;
typedef __attribute__((ext_vector_type(4))) float f32x4;
typedef __attribute__((ext_vector_type(4))) int i32x4;
typedef __attribute__((ext_vector_type(4))) unsigned u32x4;
typedef __attribute__((ext_vector_type(4))) unsigned short u16x4;

// f32 -> bf16 round-to-nearest-even (finite values only)
__device__ __forceinline__ unsigned short f2bf(float x) {
    unsigned u = __float_as_uint(x);
    u = (u + 0x7FFFu + ((u >> 16) & 1u)) >> 16;
    return (unsigned short)u;
}
__device__ __forceinline__ float bf2f(unsigned short h) {
    return __uint_as_float((unsigned)h << 16);
}
__device__ __forceinline__ float fast_exp2(float x) {
#if __has_builtin(__builtin_amdgcn_exp2f)
    return __builtin_amdgcn_exp2f(x);
#else
    return __expf(x * 0.6931471805599453f);
#endif
}
// order-preserving uint key for f32 (for atomicMax on floats of any sign)
__device__ __forceinline__ unsigned fkey(float x) {
    unsigned u = __float_as_uint(x);
    return ((int)u < 0) ? ~u : (u | 0x80000000u);
}
__device__ __forceinline__ float funkey(unsigned k) {
    unsigned u = (k & 0x80000000u) ? (k & 0x7FFFFFFFu) : ~k;
    return __uint_as_float(u);
}
// Non-temporal 16B load: no-reuse hint so adj's one-shot 256 MB stream does
// not allocate (and thus does not force dirty-poison writebacks from the
// harness's 1-GiB 0xAA fills that precede each timed launch).
__device__ __forceinline__ i32x4 ntload4(const int* p) {
    return __builtin_nontemporal_load((const i32x4*)p);
}

// ---------------------------------------------------------------------------
// prep: Wa1 = W@a1, Wa2 = W@a2 (fp32); WbT hi/lo bf16 split, [f][k]. 1 block.
// Also inits the maxS2 atomic key slot (workspace is poison-filled).
// ---------------------------------------------------------------------------
__global__ __launch_bounds__(256) void prep_kernel(
    const float* __restrict__ W, const float* __restrict__ a,
    float* __restrict__ Wa1, float* __restrict__ Wa2,
    unsigned short* __restrict__ WbTh, unsigned short* __restrict__ WbTl,
    unsigned* __restrict__ maxkey) {
    __shared__ float Wl[F_IN][F_OUT + 1];
    __shared__ float al[2 * F_OUT];
    const int t = threadIdx.x;
    if (t == 0) *maxkey = 0u;   // below every real float's key
    for (int it = 0; it < 16; ++it) {
        const int idx = it * 1024 + t * 4;
        const f32x4 v = *(const f32x4*)&W[idx];
        const int r = idx >> 6, c = idx & 63;
        Wl[r][c] = v[0]; Wl[r][c + 1] = v[1]; Wl[r][c + 2] = v[2]; Wl[r][c + 3] = v[3];
    }
    if (t < 128) al[t] = a[t];
    __syncthreads();
    float x1 = 0.f, x2 = 0.f;
#pragma unroll 8
    for (int f = 0; f < F_OUT; ++f) {
        const float wv = Wl[t][f];
        x1 += wv * al[f];
        x2 += wv * al[F_OUT + f];
    }
    Wa1[t] = x1; Wa2[t] = x2;
    const int f = t >> 2, k0 = (t & 3) * 64;
    for (int kk = 0; kk < 64; kk += 8) {
        u32x4 ph, pl;
#pragma unroll
        for (int u = 0; u < 4; ++u) {
            const float w0 = Wl[k0 + kk + 2 * u][f];
            const float w1 = Wl[k0 + kk + 2 * u + 1][f];
            const unsigned short h0 = f2bf(w0), h1 = f2bf(w1);
            const unsigned short l0 = f2bf(w0 - bf2f(h0)), l1 = f2bf(w1 - bf2f(h1));
            ph[u] = (unsigned)h0 | ((unsigned)h1 << 16);
            pl[u] = (unsigned)l0 | ((unsigned)l1 << 16);
        }
        *(u32x4*)&WbTh[f * F_IN + k0 + kk] = ph;
        *(u32x4*)&WbTl[f * F_IN + k0 + kk] = pl;
    }
}

// ---------------------------------------------------------------------------
// scores (exp2-scaled domain): s1c[i] = (h@Wa1)*log2e, s2c[i] = (h@Wa2)*log2e.
// Also reduces global maxS2 = max_i s2c[i] (one atomic per block) -- used by
// attn as a softmax shift bound (lrelu monotone => lrelu(s1+maxS2) >= any
// masked score in the row).
// ---------------------------------------------------------------------------
__global__ __launch_bounds__(256) void score_kernel(
    const float* __restrict__ h, const float* __restrict__ Wa1,
    const float* __restrict__ Wa2, float* __restrict__ s1c, float* __restrict__ s2c,
    unsigned* __restrict__ maxkey) {
    __shared__ float w1l[F_IN], w2l[F_IN];
    __shared__ float red[4];
    const int t = threadIdx.x, wave = t >> 6, lane = t & 63;
    w1l[t] = Wa1[t]; w2l[t] = Wa2[t];
    __syncthreads();
    const int row0 = blockIdx.x * 16 + wave * 4;
    const f32x4 wa1 = *(const f32x4*)&w1l[lane * 4];
    const f32x4 wa2 = *(const f32x4*)&w2l[lane * 4];
    float wmax = -3.0e38f;
#pragma unroll
    for (int r = 0; r < 4; ++r) {
        const f32x4 hv = *(const f32x4*)(h + (size_t)(row0 + r) * F_IN + lane * 4);
        float d1 = hv[0] * wa1[0] + hv[1] * wa1[1] + hv[2] * wa1[2] + hv[3] * wa1[3];
        float d2 = hv[0] * wa2[0] + hv[1] * wa2[1] + hv[2] * wa2[2] + hv[3] * wa2[3];
#pragma unroll
        for (int off = 32; off; off >>= 1) {
            d1 += __shfl_down(d1, off, 64);
            d2 += __shfl_down(d2, off, 64);
        }
        if (lane == 0) {
            const float v2 = d2 * LOG2E;
            s1c[row0 + r] = d1 * LOG2E; s2c[row0 + r] = v2;
            wmax = fmaxf(wmax, v2);
        }
    }
    if (lane == 0) red[wave] = wmax;
    __syncthreads();
    if (t == 0) {
        const float bm = fmaxf(fmaxf(red[0], red[1]), fmaxf(red[2], red[3]));
        atomicMax(maxkey, fkey(bm));
    }
}

// ---------------------------------------------------------------------------
// whT: WhT[f][i] = bf16((h@W)[i][f]) via hi/lo-split bf16 MFMA (3 products).
// grid 512 x 256: block = 16-row m-tile; wave = 16-col n-tile.
// ---------------------------------------------------------------------------
__global__ __launch_bounds__(256) void whT_kernel(
    const float* __restrict__ h, const unsigned short* __restrict__ WbTh,
    const unsigned short* __restrict__ WbTl, unsigned short* __restrict__ WhT) {
    const int t = threadIdx.x;
    const int nt = t >> 6, lane = t & 63;        // wave = n-tile
    const int mq = lane & 15, quad = lane >> 4;
    const int i0 = blockIdx.x * 16;
    const float* hp = h + (size_t)(i0 + mq) * F_IN + quad * 8;
    const unsigned short* bph = WbTh + (nt * 16 + mq) * F_IN + quad * 8;
    const unsigned short* bpl = WbTl + (nt * 16 + mq) * F_IN + quad * 8;
    f32x4 acc = {0.f, 0.f, 0.f, 0.f};
#pragma unroll
    for (int kk = 0; kk < 8; ++kk) {
        const f32x4 h0 = *(const f32x4*)(hp + kk * 32);
        const f32x4 h1 = *(const f32x4*)(hp + kk * 32 + 4);
        bf16x8 ah, al;
#pragma unroll
        for (int u = 0; u < 8; ++u) {
            const float v = (u < 4) ? h0[u] : h1[u - 4];
            const unsigned short hi = f2bf(v);
            ah[u] = (short)hi;
            al[u] = (short)f2bf(v - bf2f(hi));
        }
        const bf16x8 bh = *(const bf16x8*)(bph + kk * 32);
        const bf16x8 bl = *(const bf16x8*)(bpl + kk * 32);
        acc = __builtin_amdgcn_mfma_f32_16x16x32_bf16(ah, bh, acc, 0, 0, 0);
        acc = __builtin_amdgcn_mfma_f32_16x16x32_bf16(al, bh, acc, 0, 0, 0);
        acc = __builtin_amdgcn_mfma_f32_16x16x32_bf16(ah, bl, acc, 0, 0, 0);
    }
    u16x4 o;
#pragma unroll
    for (int r = 0; r < 4; ++r) o[r] = f2bf(acc[r]);
    *(u16x4*)&WhT[(size_t)(nt * 16 + mq) * N + i0 + quad * 4] = o;
}

// ---------------------------------------------------------------------------
// fused attn, bound-shifted softmax (NO online rescale):
// grid 512 x 512. Wave w owns cols [w*1024, w*1024+1024) of rows i0..i0+15.
// adj streamed once (nt loads, 2-deep prefetch). Weights are
//   w = exp2(e - Brow + 80),  Brow = lrelu(s1[i] + maxS2) >= true masked max,
// so w <= 2^80 (no overflow: bf16 max 2^127, f32 accum <= ~2^97) and the
// +80 offset gives ~210 exp2-units of underflow margin before the row
// denominator could vanish (worst plausible bound-gap ~100 units).
// Num and den use the same truncated-bf16 weights -> ratio identical to the
// exact-max version; the shift cancels in the final divide.
// No per-iteration cross-lane ops, no accumulator rescale: the inner loop is
// pure {stream adj, score, exp2, pack, 5 MFMA} with no serial softmax chain.
// ---------------------------------------------------------------------------
#define AROWS 16
__global__ __launch_bounds__(512, 4) void attn_kernel(
    const int* __restrict__ adj,
    const unsigned short* __restrict__ WhT,
    const float* __restrict__ s1c, const float* __restrict__ s2c,
    const unsigned* __restrict__ maxkey, float* __restrict__ out) {
    __shared__ float s1l[AROWS];
    __shared__ __align__(16) float accbuf[8][AROWS][F_OUT];   // 32 KB
    __shared__ float rowsums[8][AROWS];

    const int t = threadIdx.x, wave = t >> 6, lane = t & 63;
    const int i0 = blockIdx.x * AROWS;
    if (t < AROWS) s1l[t] = s1c[i0 + t];
    __syncthreads();

    const int mq = lane & 15, quad = lane >> 4;
    const float s1m = s1l[mq];
    const float maxS2 = funkey(*maxkey);
    // Brow = lrelu(s1m + maxS2); Bc = Brow - COFF; fold into per-lane consts:
    // p = (s1m - Bc) + s2k ; q = fma(ALPHA, s2k, ALPHA*s1m - Bc) ; e' = max(p,q)
    const float xb = s1m + maxS2;
    const float Bc = fmaxf(xb, ALPHA * xb) - COFF;
    const float c1 = s1m - Bc;
    const float c2 = ALPHA * s1m - Bc;
    const int jb0 = wave * 1024;

    const int* __restrict__ ap = adj + (size_t)(i0 + mq) * N + jb0 + quad * 8;
    const float* __restrict__ sp = s2c + jb0 + quad * 8;
    const unsigned short* __restrict__ wp = WhT + (size_t)mq * N + jb0 + quad * 8;

    f32x4 acc0 = {0.f, 0.f, 0.f, 0.f}, acc1 = acc0, acc2 = acc0, acc3 = acc0, accS = acc0;
    bf16x8 onesf;
#pragma unroll
    for (int u = 0; u < 8; ++u) onesf[u] = (mq == 0) ? (short)0x3F80 : (short)0;

    // 2-deep adj prefetch: ~4 KB/wave in flight covers ~900-cy HBM latency.
    i32x4 a0c = ntload4(ap),      a1c = ntload4(ap + 4);
    i32x4 a0n = ntload4(ap + 32), a1n = ntload4(ap + 36);

#pragma unroll 2
    for (int c = 0; c < 32; ++c) {
        i32x4 a0f = a0n, a1f = a1n;
        if (c + 2 < 32) {
            a0f = ntload4(ap + (c + 2) * 32);
            a1f = ntload4(ap + (c + 2) * 32 + 4);
        }
        const f32x4 v0 = *(const f32x4*)(sp + c * 32);
        const f32x4 v1 = *(const f32x4*)(sp + c * 32 + 4);
        const unsigned short* wpc = wp + c * 32;
        const bf16x8 b0 = *(const bf16x8*)(wpc);
        const bf16x8 b1 = *(const bf16x8*)(wpc + 16 * N);
        const bf16x8 b2 = *(const bf16x8*)(wpc + 32 * N);
        const bf16x8 b3 = *(const bf16x8*)(wpc + 48 * N);

        bf16x8 af;
#pragma unroll
        for (int jj = 0; jj < 8; ++jj) {
            const float s2k = (jj < 4) ? v0[jj] : v1[jj - 4];
            const float p = c1 + s2k;                    // x - Bc
            const float q = __builtin_fmaf(ALPHA, s2k, c2);  // ALPHA*x - Bc
            const float e = fmaxf(p, q);                 // lrelu(x) - Bc  (<= COFF)
            const int av = (jj < 4) ? a0c[jj] : a1c[jj - 4];
            const float w = (av > 0) ? fast_exp2(e) : 0.f;
            af[jj] = (short)(__float_as_uint(w) >> 16);  // truncating bf16 (num==den weights)
        }
        acc0 = __builtin_amdgcn_mfma_f32_16x16x32_bf16(af, b0, acc0, 0, 0, 0);
        acc1 = __builtin_amdgcn_mfma_f32_16x16x32_bf16(af, b1, acc1, 0, 0, 0);
        acc2 = __builtin_amdgcn_mfma_f32_16x16x32_bf16(af, b2, acc2, 0, 0, 0);
        acc3 = __builtin_amdgcn_mfma_f32_16x16x32_bf16(af, b3, acc3, 0, 0, 0);
        accS = __builtin_amdgcn_mfma_f32_16x16x32_bf16(af, onesf, accS, 0, 0, 0);
        a0c = a0n; a1c = a1n; a0n = a0f; a1n = a1f;
    }

#pragma unroll
    for (int r = 0; r < 4; ++r) {
        const int row = quad * 4 + r;                    // C-axis row
        accbuf[wave][row][0 + mq]  = acc0[r];
        accbuf[wave][row][16 + mq] = acc1[r];
        accbuf[wave][row][32 + mq] = acc2[r];
        accbuf[wave][row][48 + mq] = acc3[r];
        if (mq == 0) rowsums[wave][row] = accS[r];
    }
    __syncthreads();

    {
        // all waves share the same shift Brow -> plain sum combine
        const int row = t >> 5, f0 = (t & 31) * 2;
        float o0 = 0.f, o1 = 0.f, rs = 0.f;
#pragma unroll
        for (int w = 0; w < 8; ++w) {
            o0 += accbuf[w][row][f0];
            o1 += accbuf[w][row][f0 + 1];
            rs += rowsums[w][row];
        }
        const float inv = (rs > 0.f) ? 1.f / rs : 0.f;
        float2 st = {o0 * inv, o1 * inv};
        *(float2*)&out[(size_t)(i0 + row) * F_OUT + f0] = st;
    }
}

extern "C" void kernel_launch(void* const* d_in, const int* in_sizes, int n_in,
                              void* d_out, int out_size, void* d_ws, size_t ws_size,
                              hipStream_t stream) {
    const float* h   = (const float*)d_in[0];
    const int*   adj = (const int*)d_in[1];
    const float* W   = (const float*)d_in[2];
    const float* a   = (const float*)d_in[3];
    float* out = (float*)d_out;

    // workspace layout (~1.2 MB)
    char* ws = (char*)d_ws;
    unsigned short* WhT = (unsigned short*)ws;                           // 1 MB
    float* s1c  = (float*)(ws + (size_t)F_OUT * N * 2);                  // 32 KB
    float* s2c  = s1c + N;                                               // 32 KB
    float* Wa1  = s2c + N;
    float* Wa2  = Wa1 + F_IN;
    unsigned short* WbTh = (unsigned short*)(Wa2 + F_IN);                // 32 KB
    unsigned short* WbTl = WbTh + F_OUT * F_IN;                          // 32 KB
    unsigned* maxkey = (unsigned*)(WbTl + F_OUT * F_IN);                 // 4 B

    prep_kernel<<<1, 256, 0, stream>>>(W, a, Wa1, Wa2, WbTh, WbTl, maxkey);
    score_kernel<<<N / 16, 256, 0, stream>>>(h, Wa1, Wa2, s1c, s2c, maxkey);
    whT_kernel<<<N / 16, 256, 0, stream>>>(h, WbTh, WbTl, WhT);
    attn_kernel<<<N / AROWS, 512, 0, stream>>>(adj, WhT, s1c, s2c, maxkey, out);
}